// Round 13
// baseline (70.227 us; speedup 1.0000x reference)
//
#include <hip/hip_runtime.h>
#include <hip/hip_bf16.h>
#include <stdint.h>

#define EMB 1024
#define NB 8
#define SEQ 2048
#define RANK 8
#define SPLIT 4    // KV splits in flash attention

// proj geometry
#define BM 32      // rows per block
#define BK 64      // k per stage
#define NSTG 16    // EMB/BK
#define BUFB 8192  // 8KB X(fp32) per stage buffer (W goes L2->registers)
#define NBUF 3     // 24KB dynamic LDS -> 2 blocks/CU

typedef __attribute__((ext_vector_type(8))) short bf16x8;
typedef __attribute__((ext_vector_type(4))) float f32x4;
typedef unsigned short u16;
typedef unsigned int u32;

__device__ __forceinline__ u16 f2bf(float f) {
  u32 u = __builtin_bit_cast(u32, f);
  u = (u + 0x7fffu + ((u >> 16) & 1u)) >> 16;   // RNE
  return (u16)u;
}
__device__ __forceinline__ u32 pk2(float lo, float hi) {
  return (u32)f2bf(lo) | ((u32)f2bf(hi) << 16);
}
__device__ __forceinline__ u32 cvtpk(float lo, float hi) {
  __hip_bfloat162 h = __float22bfloat162_rn(make_float2(lo, hi));  // HW pk cvt, RNE
  u32 u; __builtin_memcpy(&u, &h, 4); return u;
}
__device__ __forceinline__ void gll16(const void* g, void* l) {
  __builtin_amdgcn_global_load_lds(
      (const __attribute__((address_space(1))) unsigned int*)g,
      (__attribute__((address_space(3))) unsigned int*)l, 16, 0, 0);
}

#define PBAR()   asm volatile("s_barrier" ::: "memory")
#define WAITV(n) asm volatile("s_waitcnt vmcnt(" #n ")" ::: "memory")

// ---------------- fold: Weff[m][e] = W[h][e] + 2*sum_r B[h][r]*A[r][e]
__global__ __launch_bounds__(256) void fold_k(
    const float* __restrict__ Wq, const float* __restrict__ Wk, const float* __restrict__ Wv,
    const float* __restrict__ Aq, const float* __restrict__ Bq,
    const float* __restrict__ Ak, const float* __restrict__ Bk,
    const float* __restrict__ Av, const float* __restrict__ Bv,
    u16* __restrict__ weff) {
  int m = blockIdx.x;
  int mat = m >> 6, h = m & 63;
  const float* W = mat == 0 ? Wq : (mat == 1 ? Wk : Wv);
  const float* A = mat == 0 ? Aq : (mat == 1 ? Ak : Av);
  const float* B = mat == 0 ? Bq : (mat == 1 ? Bk : Bv);
  float bb[RANK];
#pragma unroll
  for (int r = 0; r < RANK; r++) bb[r] = 2.0f * B[h * RANK + r];
  int e = threadIdx.x * 4;
  float4 w4 = *(const float4*)(W + h * EMB + e);
  float a0 = w4.x, a1 = w4.y, a2 = w4.z, a3 = w4.w;
#pragma unroll
  for (int r = 0; r < RANK; r++) {
    float4 av = *(const float4*)(A + r * EMB + e);
    a0 += bb[r] * av.x; a1 += bb[r] * av.y; a2 += bb[r] * av.z; a3 += bb[r] * av.w;
  }
  u16* o = weff + (size_t)m * EMB + e;
  o[0] = f2bf(a0); o[1] = f2bf(a1); o[2] = f2bf(a2); o[3] = f2bf(a3);
}

// ---------------- projection GEMM: C[16384,192] = X * Weff^T
// 512 blocks x 320 thr (5 waves), 32 rows/block, 2 blocks/CU (24KB dyn LDS).
// Two independent pipelines per CU overlap each other's stalls.
// Waves 3-4 = producers: 4 gll16/stage each (X fp32, source-XOR-swizzled),
// issued 2 stages ahead, counted WAITV(4) steady-state, 1 s_barrier/stage.
// Waves 0-2 = consumers: 32 rows x 64 cols each; A from LDS (fp32 swizzled +
// pk-cvt); W fragments loaded straight from L2 into registers with 1-stage
// prefetch (compiler-managed waits); 16 MFMA/stage.
__global__ __launch_bounds__(320) void proj_k(
    const float* __restrict__ X, const u16* __restrict__ weff,
    u16* __restrict__ qws, u16* __restrict__ kws, u16* __restrict__ vws) {
  extern __shared__ __align__(16) char smem[];   // NBUF * BUFB = 24KB

  int t = threadIdx.x;
  int w = t >> 6, l = t & 63;
  int rbase = blockIdx.x * BM;

  if (w >= 3) {
    // ======== producers (waves 3,4): X only ========
    int q = w - 3;                           // 0,1 -> rows q*16 .. q*16+15
    int lr4 = l >> 4;                        // 0..3 row-in-instr
    int l15 = l & 15;                        // 16B slot

#define ISSUE(st, bufp) do {                                                   \
    _Pragma("unroll")                                                          \
    for (int i_ = 0; i_ < 4; i_++) {                                           \
      int rrel_ = q * 16 + i_ * 4 + lr4;                                       \
      int xo_ = 4 * (l15 ^ (rrel_ & 7));     /* X source swizzle (floats) */   \
      gll16(X + (size_t)(rbase + rrel_) * EMB + (st) * BK + xo_,               \
            (bufp) + q * 4096 + i_ * 1024);                                    \
    } } while (0)

    ISSUE(0, smem);
    ISSUE(1, smem + BUFB);
    WAITV(4);                                // batch 0 landed
    for (int s = 0; s < NSTG; s++) {
      PBAR();                                // consumers start stage s
      if (s + 2 < NSTG) {
        ISSUE(s + 2, smem + ((s + 2) % NBUF) * BUFB);
        WAITV(4);                            // batch s+1 landed
      } else {
        WAITV(0);                            // drain tail
      }
    }
#undef ISSUE
  } else {
    // ======== consumers (waves 0-2): 32 rows x cols [w*64, w*64+64) ========
    int l15 = l & 15, lh = l >> 4;
    f32x4 acc[2][4];
    f32x4 zero = {0.f, 0.f, 0.f, 0.f};
#pragma unroll
    for (int rt = 0; rt < 2; rt++)
#pragma unroll
      for (int ct = 0; ct < 4; ct++) acc[rt][ct] = zero;

    const u16* wp[4];
#pragma unroll
    for (int ct = 0; ct < 4; ct++)
      wp[ct] = weff + (size_t)(w * 64 + ct * 16 + l15) * EMB + lh * 8;

    bf16x8 wc[2][4], wn[2][4];
#pragma unroll
    for (int j = 0; j < 2; j++)
#pragma unroll
      for (int ct = 0; ct < 4; ct++)
        wc[j][ct] = *(const bf16x8*)(wp[ct] + j * 32);

    for (int s = 0; s < NSTG; s++) {
      PBAR();
      if (s + 1 < NSTG) {                     // W(s+1) -> regs (L2, prefetch)
#pragma unroll
        for (int j = 0; j < 2; j++)
#pragma unroll
          for (int ct = 0; ct < 4; ct++)
            wn[j][ct] = *(const bf16x8*)(wp[ct] + (s + 1) * BK + j * 32);
      }
      const char* bx = smem + (s % NBUF) * BUFB;   // X fp32 [32][256B] swz
#pragma unroll
      for (int j = 0; j < 2; j++) {
        bf16x8 a[2];
#pragma unroll
        for (int rt = 0; rt < 2; rt++) {
          int r = rt * 16 + l15;
          int sw = (r & 7) << 4;
          const char* base = bx + r * 256;
          f32x4 lo = *(const f32x4*)(base + ((j * 128 + lh * 32) ^ sw));
          f32x4 hi = *(const f32x4*)(base + ((j * 128 + lh * 32 + 16) ^ sw));
          union { bf16x8 v; u32 u[4]; } au;
          au.u[0] = cvtpk(lo.x, lo.y); au.u[1] = cvtpk(lo.z, lo.w);
          au.u[2] = cvtpk(hi.x, hi.y); au.u[3] = cvtpk(hi.z, hi.w);
          a[rt] = au.v;
        }
        __builtin_amdgcn_s_setprio(1);
#pragma unroll
        for (int ct = 0; ct < 4; ct++)
#pragma unroll
          for (int rt = 0; rt < 2; rt++)
            acc[rt][ct] = __builtin_amdgcn_mfma_f32_16x16x32_bf16(a[rt], wc[j][ct], acc[rt][ct], 0, 0, 0);
        __builtin_amdgcn_s_setprio(0);
      }
#pragma unroll
      for (int j = 0; j < 2; j++)
#pragma unroll
        for (int ct = 0; ct < 4; ct++) wc[j][ct] = wn[j][ct];
    }

    // epilogue: scatter to q (x0.125 folded) / k / v^T (bf16)
#pragma unroll
    for (int rt = 0; rt < 2; rt++)
#pragma unroll
      for (int ct = 0; ct < 4; ct++) {
        int c = w * 64 + ct * 16 + l15;
#pragma unroll
        for (int r = 0; r < 4; r++) {
          int rr = rbase + rt * 16 + lh * 4 + r;
          float av = acc[rt][ct][r];
          if (c < 64) av *= 0.125f;
          u16 v = f2bf(av);
          if (c < 64) {
            qws[(size_t)rr * 64 + c] = v;
          } else if (c < 128) {
            kws[(size_t)rr * 64 + (c - 64)] = v;
          } else {
            int bb = rr >> 11, tok = rr & 2047;
            vws[((size_t)(bb * 64 + (c - 128))) * SEQ + tok] = v;
          }
        }
      }
  }
}

// ---------------- flash attention, KV-split: grid (32 qtiles, 8 batch, SPLIT).
__global__ __launch_bounds__(256) void attn_k(
    const u16* __restrict__ qws, const u16* __restrict__ kws, const u16* __restrict__ vws,
    const int* __restrict__ mrk,
    float* __restrict__ po, float* __restrict__ pmp, float* __restrict__ plp) {
  __shared__ __align__(16) u16 ks[2 * 4096];
  __shared__ __align__(16) u16 vt[2 * 4096];
  __shared__ __align__(16) u16 ps[4 * 1024];

  int b = blockIdx.y;
  int z = blockIdx.z;
  int q0 = blockIdx.x * 64;
  int t = threadIdx.x;
  int w = t >> 6, l = t & 63;
  int l15 = l & 15, lh = l >> 4;

  int srow = t >> 3;
  int ssw = (((t & 7) << 4) ^ ((srow & 7) << 4)) >> 1;
  char* ksb = (char*)ks + w * 1024;
  char* vtb = (char*)vt + w * 1024;

  const u16* qp = qws + ((size_t)(b * SEQ + q0 + w * 16 + l15)) * 64 + lh * 8;
  bf16x8 qb0 = *(const bf16x8*)qp;
  bf16x8 qb1 = *(const bf16x8*)(qp + 32);

  f32x4 o[4];
  f32x4 zero = {0.f, 0.f, 0.f, 0.f};
#pragma unroll
  for (int ht = 0; ht < 4; ht++) o[ht] = zero;
  float mrow = -30000.0f, lrow = 0.f;

  int swz = (l15 & 7) << 4;
  int koffA = ((lh << 4) ^ swz) >> 1;
  int koffB = ((64 | (lh << 4)) ^ swz) >> 1;
  u16* psw = ps + w * 1024 + l15 * 64;

  const int NC = SEQ / 64 / SPLIT;
  int kk0 = z * (SEQ / SPLIT);

#define STAGE_KV(buf, kk)                                                          \
  do {                                                                             \
    gll16(kws + ((size_t)(b * SEQ + (kk) + srow)) * 64 + ssw,                      \
          ksb + (buf) * 8192);                                                     \
    gll16(kws + ((size_t)(b * SEQ + (kk) + srow + 32)) * 64 + ssw,                 \
          ksb + (buf) * 8192 + 4096);                                              \
    gll16(vws + ((size_t)(b * 64 + srow)) * SEQ + (kk) + ssw,                      \
          vtb + (buf) * 8192);                                                     \
    gll16(vws + ((size_t)(b * 64 + srow + 32)) * SEQ + (kk) + ssw,                 \
          vtb + (buf) * 8192 + 4096);                                              \
  } while (0)

  STAGE_KV(0, kk0);
  __syncthreads();

  int cur = 0;
  for (int kc = 0; kc < NC; kc++) {
    int kk = kk0 + kc * 64;
    if (kc + 1 < NC) STAGE_KV(cur ^ 1, kk + 64);

    int4 mi[4];
#pragma unroll
    for (int nt = 0; nt < 4; nt++)
      mi[nt] = *(const int4*)(mrk + b * SEQ + kk + nt * 16 + lh * 4);

    const u16* kb = ks + cur * 4096;
    f32x4 sa[4];
    __builtin_amdgcn_s_setprio(1);
#pragma unroll
    for (int nt = 0; nt < 4; nt++) {
      const u16* kr = kb + (nt * 16 + l15) * 64;
      bf16x8 k0 = *(const bf16x8*)(kr + koffA);
      bf16x8 k1 = *(const bf16x8*)(kr + koffB);
      f32x4 s = zero;
      s = __builtin_amdgcn_mfma_f32_16x16x32_bf16(k0, qb0, s, 0, 0, 0);
      s = __builtin_amdgcn_mfma_f32_16x16x32_bf16(k1, qb1, s, 0, 0, 0);
      sa[nt] = s;
    }
    __builtin_amdgcn_s_setprio(0);

    const u16* vbb = vt + cur * 4096;
    bf16x8 vb[4][2];
#pragma unroll
    for (int ht = 0; ht < 4; ht++) {
      const u16* vr = vbb + (ht * 16 + l15) * 64;
      vb[ht][0] = *(const bf16x8*)(vr + koffA);
      vb[ht][1] = *(const bf16x8*)(vr + koffB);
    }

#pragma unroll
    for (int nt = 0; nt < 4; nt++) {
      sa[nt][0] = mi[nt].x ? sa[nt][0] : -INFINITY;
      sa[nt][1] = mi[nt].y ? sa[nt][1] : -INFINITY;
      sa[nt][2] = mi[nt].z ? sa[nt][2] : -INFINITY;
      sa[nt][3] = mi[nt].w ? sa[nt][3] : -INFINITY;
    }
    float t0 = fmaxf(fmaxf(sa[0][0], sa[0][1]), fmaxf(sa[0][2], sa[0][3]));
    float t1 = fmaxf(fmaxf(sa[1][0], sa[1][1]), fmaxf(sa[1][2], sa[1][3]));
    float t2 = fmaxf(fmaxf(sa[2][0], sa[2][1]), fmaxf(sa[2][2], sa[2][3]));
    float t3 = fmaxf(fmaxf(sa[3][0], sa[3][1]), fmaxf(sa[3][2], sa[3][3]));
    float tm = fmaxf(fmaxf(t0, t1), fmaxf(t2, t3));
    tm = fmaxf(tm, __shfl_xor(tm, 16));
    tm = fmaxf(tm, __shfl_xor(tm, 32));

    if (!__all(tm <= mrow + 8.0f)) {       // defer-max (T13)
      float nm = fmaxf(mrow, tm);
      float alpha = __expf(mrow - nm);
      mrow = nm;
      lrow *= alpha;
      float a0 = __shfl(alpha, lh * 4 + 0);
      float a1 = __shfl(alpha, lh * 4 + 1);
      float a2 = __shfl(alpha, lh * 4 + 2);
      float a3 = __shfl(alpha, lh * 4 + 3);
#pragma unroll
      for (int ht = 0; ht < 4; ht++) {
        o[ht][0] *= a0; o[ht][1] *= a1; o[ht][2] *= a2; o[ht][3] *= a3;
      }
    }

    float ts = 0.f;
#pragma unroll
    for (int nt = 0; nt < 4; nt++) {
#pragma unroll
      for (int r = 0; r < 4; r++) {
        float p = __expf(sa[nt][r] - mrow);
        sa[nt][r] = p;
        ts += p;
      }
    }
    ts += __shfl_xor(ts, 16);
    ts += __shfl_xor(ts, 32);
    lrow += ts;

#pragma unroll
    for (int nt = 0; nt < 4; nt++) {
      u32 plo = pk2(sa[nt][0], sa[nt][1]);
      u32 phi = pk2(sa[nt][2], sa[nt][3]);
      *(uint2*)&psw[(((nt * 32 + lh * 8) ^ swz) >> 1)] = make_uint2(plo, phi);
    }
    bf16x8 ap0 = *(const bf16x8*)(psw + koffA);
    bf16x8 ap1 = *(const bf16x8*)(psw + koffB);

    __builtin_amdgcn_s_setprio(1);
#pragma unroll
    for (int ht = 0; ht < 4; ht++) {
      o[ht] = __builtin_amdgcn_mfma_f32_16x16x32_bf16(ap0, vb[ht][0], o[ht], 0, 0, 0);
      o[ht] = __builtin_amdgcn_mfma_f32_16x16x32_bf16(ap1, vb[ht][1], o[ht], 0, 0, 0);
    }
    __builtin_amdgcn_s_setprio(0);
    __syncthreads();
    cur ^= 1;
  }
#undef STAGE_KV

#pragma unroll
  for (int r = 0; r < 4; r++) {
    int rr = q0 + w * 16 + lh * 4 + r;
    float* pob = po + ((size_t)z * NB * SEQ + (size_t)b * SEQ + rr) * 64;
#pragma unroll
    for (int ht = 0; ht < 4; ht++) pob[ht * 16 + l15] = o[ht][r];
  }
  if (lh == 0) {
    int rr = q0 + w * 16 + l15;
    pmp[(size_t)z * NB * SEQ + (size_t)b * SEQ + rr] = mrow;
    plp[(size_t)z * NB * SEQ + (size_t)b * SEQ + rr] = lrow;
  }
}

// ---------------- merge SPLIT partials -> fp32 out
__global__ __launch_bounds__(256) void merge_k(
    const float* __restrict__ po, const float* __restrict__ pmp,
    const float* __restrict__ plp, float* __restrict__ out) {
  int tid = threadIdx.x;
  int row = blockIdx.x * 32 + (tid >> 3);
  int c8 = (tid & 7) * 8;
  const int RT = NB * SEQ;

  float m[SPLIT], lv[SPLIT];
  float M = -INFINITY;
#pragma unroll
  for (int s = 0; s < SPLIT; s++) {
    m[s] = pmp[(size_t)s * RT + row];
    lv[s] = plp[(size_t)s * RT + row];
    M = fmaxf(M, m[s]);
  }
  float o8[8];
#pragma unroll
  for (int j = 0; j < 8; j++) o8[j] = 0.f;
  float L = 0.f;
  if (M != -INFINITY) {
#pragma unroll
    for (int s = 0; s < SPLIT; s++) {
      float ws = __expf(m[s] - M);
      L += ws * lv[s];
      const float* p = po + ((size_t)s * RT + row) * 64 + c8;
#pragma unroll
      for (int j = 0; j < 8; j++) o8[j] += ws * p[j];
    }
  }
  float inv = (L > 0.f) ? 1.0f / L : 0.f;
  float* op = out + (size_t)row * 64 + c8;
#pragma unroll
  for (int j = 0; j < 8; j++) op[j] = o8[j] * inv;
}

extern "C" void kernel_launch(void* const* d_in, const int* in_sizes, int n_in,
                              void* d_out, int out_size, void* d_ws, size_t ws_size,
                              hipStream_t stream) {
  const float* X   = (const float*)d_in[0];
  const int*   mrk = (const int*)d_in[1];
  const float* Wq  = (const float*)d_in[2];
  const float* Wk  = (const float*)d_in[3];
  const float* Wv  = (const float*)d_in[4];
  const float* Aq  = (const float*)d_in[5];
  const float* Bq  = (const float*)d_in[6];
  const float* Ak  = (const float*)d_in[7];
  const float* Bk  = (const float*)d_in[8];
  const float* Av  = (const float*)d_in[9];
  const float* Bv  = (const float*)d_in[10];

  u16* weff = (u16*)d_ws;
  u16* qws  = (u16*)((char*)d_ws + (512 << 10));
  u16* kws  = qws + (size_t)16384 * 64;
  u16* vws  = kws + (size_t)16384 * 64;
  float* po  = (float*)((char*)d_ws + ((size_t)6656 << 10));
  float* pmp = po + (size_t)SPLIT * 16384 * 64;
  float* plp = pmp + (size_t)SPLIT * 16384;

  (void)hipFuncSetAttribute((const void*)proj_k,
                            hipFuncAttributeMaxDynamicSharedMemorySize, NBUF * BUFB);

  fold_k<<<192, 256, 0, stream>>>(Wq, Wk, Wv, Aq, Bq, Ak, Bk, Av, Bv, weff);
  proj_k<<<512, 320, NBUF * BUFB, stream>>>(X, weff, qws, kws, vws);
  attn_k<<<dim3(32, 8, SPLIT), 256, 0, stream>>>(qws, kws, vws, mrk, po, pmp, plp);
  merge_k<<<512, 256, 0, stream>>>(po, pmp, plp, (float*)d_out);
}

// Round 14
// 59.078 us; speedup vs baseline: 1.1887x; 1.1887x over previous
//
#include <hip/hip_runtime.h>
#include <hip/hip_bf16.h>
#include <stdint.h>

#define EMB 1024
#define NB 8
#define SEQ 2048
#define RANK 8
#define SPLIT 4    // KV splits in flash attention

// proj geometry
#define BM 32      // rows per block
#define BK 64      // k per stage
#define NSTG 16    // EMB/BK
#define XBUF 8192  // X fp32 per stage (32 rows x 256B)
#define WBUF 24576 // W bf16 per stage (192 cols x 128B)
// LDS: 3*XBUF + 2*WBUF = 72KB -> 2 blocks/CU

typedef __attribute__((ext_vector_type(8))) short bf16x8;
typedef __attribute__((ext_vector_type(4))) float f32x4;
typedef unsigned short u16;
typedef unsigned int u32;

__device__ __forceinline__ u16 f2bf(float f) {
  u32 u = __builtin_bit_cast(u32, f);
  u = (u + 0x7fffu + ((u >> 16) & 1u)) >> 16;   // RNE
  return (u16)u;
}
__device__ __forceinline__ u32 pk2(float lo, float hi) {
  return (u32)f2bf(lo) | ((u32)f2bf(hi) << 16);
}
__device__ __forceinline__ u32 cvtpk(float lo, float hi) {
  __hip_bfloat162 h = __float22bfloat162_rn(make_float2(lo, hi));  // HW pk cvt, RNE
  u32 u; __builtin_memcpy(&u, &h, 4); return u;
}
__device__ __forceinline__ void gll16(const void* g, void* l) {
  __builtin_amdgcn_global_load_lds(
      (const __attribute__((address_space(1))) unsigned int*)g,
      (__attribute__((address_space(3))) unsigned int*)l, 16, 0, 0);
}

#define PBAR()   asm volatile("s_barrier" ::: "memory")
#define WAITV(n) asm volatile("s_waitcnt vmcnt(" #n ")" ::: "memory")

// ---------------- fold: Weff[m][e] = W[h][e] + 2*sum_r B[h][r]*A[r][e]
__global__ __launch_bounds__(256) void fold_k(
    const float* __restrict__ Wq, const float* __restrict__ Wk, const float* __restrict__ Wv,
    const float* __restrict__ Aq, const float* __restrict__ Bq,
    const float* __restrict__ Ak, const float* __restrict__ Bk,
    const float* __restrict__ Av, const float* __restrict__ Bv,
    u16* __restrict__ weff) {
  int m = blockIdx.x;
  int mat = m >> 6, h = m & 63;
  const float* W = mat == 0 ? Wq : (mat == 1 ? Wk : Wv);
  const float* A = mat == 0 ? Aq : (mat == 1 ? Ak : Av);
  const float* B = mat == 0 ? Bq : (mat == 1 ? Bk : Bv);
  float bb[RANK];
#pragma unroll
  for (int r = 0; r < RANK; r++) bb[r] = 2.0f * B[h * RANK + r];
  int e = threadIdx.x * 4;
  float4 w4 = *(const float4*)(W + h * EMB + e);
  float a0 = w4.x, a1 = w4.y, a2 = w4.z, a3 = w4.w;
#pragma unroll
  for (int r = 0; r < RANK; r++) {
    float4 av = *(const float4*)(A + r * EMB + e);
    a0 += bb[r] * av.x; a1 += bb[r] * av.y; a2 += bb[r] * av.z; a3 += bb[r] * av.w;
  }
  u16* o = weff + (size_t)m * EMB + e;
  o[0] = f2bf(a0); o[1] = f2bf(a1); o[2] = f2bf(a2); o[3] = f2bf(a3);
}

// ---------------- projection GEMM: C[16384,192] = X * Weff^T
// 512 blocks x 320 thr, 32 rows/block, 72KB LDS -> 2 blocks/CU: two
// independent pipelines per CU overlap each other's barrier/latency stalls.
// Waves 3-4 = producers: per stage issue W(s+1) [12 gll16] then X(s+2)
// [4 gll16]; WAITV(4) leaves only X(s+2) in flight (in-order queue => W(s+1)
// landed); WAITV(0) on tail. 16 barrier events, paired with consumers.
// Waves 0-2 = consumers: 32 rows x 64 cols each; fp32 A swizzled + pk-cvt;
// W bf16 from LDS swizzled; 16 MFMA/stage; no vmem.
__global__ __launch_bounds__(320) void proj_k(
    const float* __restrict__ X, const u16* __restrict__ weff,
    u16* __restrict__ qws, u16* __restrict__ kws, u16* __restrict__ vws) {
  extern __shared__ __align__(16) char smem[];   // 3*XBUF + 2*WBUF = 72KB
  char* xsm = smem;
  char* wsm = smem + 3 * XBUF;

  int t = threadIdx.x;
  int w = t >> 6, l = t & 63;
  int rbase = blockIdx.x * BM;

  if (w >= 3) {
    // ======== producers (waves 3,4) ========
    int q = w - 3;                           // 0,1
    int lr4 = l >> 4;                        // 0..3 row-in-instr
    int l15 = l & 15;                        // 16B slot
    int wc0 = l >> 3;
    int wkoff = ((l & 7) ^ wc0) * 8;         // W source swizzle (elems)

#define ISSX(st, bufp) do {                                                    \
    _Pragma("unroll")                                                          \
    for (int i_ = 0; i_ < 2; i_++) {                                           \
      int rrel_ = q * 16 + i_ * 8 + lr4 * 2 + (l15 >> 3);                      \
      int sl_ = l15 & 7;  /* wrong path guard */                               \
      (void)sl_;                                                               \
    } } while (0)
    // (X issue below uses the R13-proven 4-instr form)
#undef ISSX

#define ISSUE_X(st, bufp) do {                                                 \
    _Pragma("unroll")                                                          \
    for (int i_ = 0; i_ < 4; i_++) {                                           \
      int rrel_ = q * 16 + i_ * 4 + lr4;                                       \
      int xo_ = 4 * (l15 ^ (rrel_ & 7));     /* X source swizzle (floats) */   \
      gll16(X + (size_t)(rbase + rrel_) * EMB + (st) * BK + xo_,               \
            (bufp) + q * 4096 + i_ * 1024);                                    \
    } } while (0)

#define ISSUE_W(st, bufp) do {                                                 \
    _Pragma("unroll")                                                          \
    for (int i_ = 0; i_ < 12; i_++) { int wj_ = q * 12 + i_;                   \
      gll16(weff + (size_t)(wj_ * 8 + wc0) * EMB + (st) * BK + wkoff,          \
            (bufp) + wj_ * 1024);                                              \
    } } while (0)

    // prologue: W0, X0, X1 in queue; wait so only X1 may remain in flight
    ISSUE_W(0, wsm);
    ISSUE_X(0, xsm);
    ISSUE_X(1, xsm + XBUF);
    WAITV(4);
    PBAR();                                  // event 0: stage 0 begins
    for (int s = 0; s < NSTG; s++) {
      if (s + 1 < NSTG) ISSUE_W(s + 1, wsm + ((s + 1) & 1) * WBUF);
      if (s + 2 < NSTG) ISSUE_X(s + 2, xsm + ((s + 2) % 3) * XBUF);
      if (s + 1 < NSTG) {
        if (s + 2 < NSTG) { WAITV(4); } else { WAITV(0); }
        PBAR();                              // event s+1
      }
      // s == NSTG-1: nothing to issue, no barrier; fall through and exit
    }
#undef ISSUE_X
#undef ISSUE_W
  } else {
    // ======== consumers (waves 0-2): 32 rows x cols [w*64, w*64+64) ========
    int l15 = l & 15, lh = l >> 4;
    f32x4 acc[2][4];
    f32x4 zero = {0.f, 0.f, 0.f, 0.f};
#pragma unroll
    for (int rt = 0; rt < 2; rt++)
#pragma unroll
      for (int ct = 0; ct < 4; ct++) acc[rt][ct] = zero;

    for (int s = 0; s < NSTG; s++) {
      PBAR();                                // event s
      const char* bx = xsm + (s % 3) * XBUF;     // X fp32 [32][256B] swz
      const char* bw = wsm + (s & 1) * WBUF;     // W bf16 [192][128B] swz
#pragma unroll
      for (int j = 0; j < 2; j++) {
        bf16x8 a[2];
#pragma unroll
        for (int rt = 0; rt < 2; rt++) {
          int r = rt * 16 + l15;
          int sw = (r & 7) << 4;
          const char* base = bx + r * 256;
          f32x4 lo = *(const f32x4*)(base + ((j * 128 + lh * 32) ^ sw));
          f32x4 hi = *(const f32x4*)(base + ((j * 128 + lh * 32 + 16) ^ sw));
          union { bf16x8 v; u32 u[4]; } au;
          au.u[0] = cvtpk(lo.x, lo.y); au.u[1] = cvtpk(lo.z, lo.w);
          au.u[2] = cvtpk(hi.x, hi.y); au.u[3] = cvtpk(hi.z, hi.w);
          a[rt] = au.v;
        }
        __builtin_amdgcn_s_setprio(1);
#pragma unroll
        for (int ct = 0; ct < 4; ct++) {
          int col = w * 64 + ct * 16 + l15;
          bf16x8 bf = *(const bf16x8*)(bw + col * 128 +
                                       ((j * 64 + lh * 16) ^ ((col & 7) << 4)));
#pragma unroll
          for (int rt = 0; rt < 2; rt++)
            acc[rt][ct] = __builtin_amdgcn_mfma_f32_16x16x32_bf16(a[rt], bf, acc[rt][ct], 0, 0, 0);
        }
        __builtin_amdgcn_s_setprio(0);
      }
    }

    // epilogue: scatter to q (x0.125 folded) / k / v^T (bf16)
#pragma unroll
    for (int rt = 0; rt < 2; rt++)
#pragma unroll
      for (int ct = 0; ct < 4; ct++) {
        int c = w * 64 + ct * 16 + l15;
#pragma unroll
        for (int r = 0; r < 4; r++) {
          int rr = rbase + rt * 16 + lh * 4 + r;
          float av = acc[rt][ct][r];
          if (c < 64) av *= 0.125f;
          u16 v = f2bf(av);
          if (c < 64) {
            qws[(size_t)rr * 64 + c] = v;
          } else if (c < 128) {
            kws[(size_t)rr * 64 + (c - 64)] = v;
          } else {
            int bb = rr >> 11, tok = rr & 2047;
            vws[((size_t)(bb * 64 + (c - 128))) * SEQ + tok] = v;
          }
        }
      }
  }
}

// ---------------- flash attention, KV-split: grid (32 qtiles, 8 batch, SPLIT).
__global__ __launch_bounds__(256) void attn_k(
    const u16* __restrict__ qws, const u16* __restrict__ kws, const u16* __restrict__ vws,
    const int* __restrict__ mrk,
    float* __restrict__ po, float* __restrict__ pmp, float* __restrict__ plp) {
  __shared__ __align__(16) u16 ks[2 * 4096];
  __shared__ __align__(16) u16 vt[2 * 4096];
  __shared__ __align__(16) u16 ps[4 * 1024];

  int b = blockIdx.y;
  int z = blockIdx.z;
  int q0 = blockIdx.x * 64;
  int t = threadIdx.x;
  int w = t >> 6, l = t & 63;
  int l15 = l & 15, lh = l >> 4;

  int srow = t >> 3;
  int ssw = (((t & 7) << 4) ^ ((srow & 7) << 4)) >> 1;
  char* ksb = (char*)ks + w * 1024;
  char* vtb = (char*)vt + w * 1024;

  const u16* qp = qws + ((size_t)(b * SEQ + q0 + w * 16 + l15)) * 64 + lh * 8;
  bf16x8 qb0 = *(const bf16x8*)qp;
  bf16x8 qb1 = *(const bf16x8*)(qp + 32);

  f32x4 o[4];
  f32x4 zero = {0.f, 0.f, 0.f, 0.f};
#pragma unroll
  for (int ht = 0; ht < 4; ht++) o[ht] = zero;
  float mrow = -30000.0f, lrow = 0.f;

  int swz = (l15 & 7) << 4;
  int koffA = ((lh << 4) ^ swz) >> 1;
  int koffB = ((64 | (lh << 4)) ^ swz) >> 1;
  u16* psw = ps + w * 1024 + l15 * 64;

  const int NC = SEQ / 64 / SPLIT;
  int kk0 = z * (SEQ / SPLIT);

#define STAGE_KV(buf, kk)                                                          \
  do {                                                                             \
    gll16(kws + ((size_t)(b * SEQ + (kk) + srow)) * 64 + ssw,                      \
          ksb + (buf) * 8192);                                                     \
    gll16(kws + ((size_t)(b * SEQ + (kk) + srow + 32)) * 64 + ssw,                 \
          ksb + (buf) * 8192 + 4096);                                              \
    gll16(vws + ((size_t)(b * 64 + srow)) * SEQ + (kk) + ssw,                      \
          vtb + (buf) * 8192);                                                     \
    gll16(vws + ((size_t)(b * 64 + srow + 32)) * SEQ + (kk) + ssw,                 \
          vtb + (buf) * 8192 + 4096);                                              \
  } while (0)

  STAGE_KV(0, kk0);
  __syncthreads();

  int cur = 0;
  for (int kc = 0; kc < NC; kc++) {
    int kk = kk0 + kc * 64;
    if (kc + 1 < NC) STAGE_KV(cur ^ 1, kk + 64);

    int4 mi[4];
#pragma unroll
    for (int nt = 0; nt < 4; nt++)
      mi[nt] = *(const int4*)(mrk + b * SEQ + kk + nt * 16 + lh * 4);

    const u16* kb = ks + cur * 4096;
    f32x4 sa[4];
    __builtin_amdgcn_s_setprio(1);
#pragma unroll
    for (int nt = 0; nt < 4; nt++) {
      const u16* kr = kb + (nt * 16 + l15) * 64;
      bf16x8 k0 = *(const bf16x8*)(kr + koffA);
      bf16x8 k1 = *(const bf16x8*)(kr + koffB);
      f32x4 s = zero;
      s = __builtin_amdgcn_mfma_f32_16x16x32_bf16(k0, qb0, s, 0, 0, 0);
      s = __builtin_amdgcn_mfma_f32_16x16x32_bf16(k1, qb1, s, 0, 0, 0);
      sa[nt] = s;
    }
    __builtin_amdgcn_s_setprio(0);

    const u16* vbb = vt + cur * 4096;
    bf16x8 vb[4][2];
#pragma unroll
    for (int ht = 0; ht < 4; ht++) {
      const u16* vr = vbb + (ht * 16 + l15) * 64;
      vb[ht][0] = *(const bf16x8*)(vr + koffA);
      vb[ht][1] = *(const bf16x8*)(vr + koffB);
    }

#pragma unroll
    for (int nt = 0; nt < 4; nt++) {
      sa[nt][0] = mi[nt].x ? sa[nt][0] : -INFINITY;
      sa[nt][1] = mi[nt].y ? sa[nt][1] : -INFINITY;
      sa[nt][2] = mi[nt].z ? sa[nt][2] : -INFINITY;
      sa[nt][3] = mi[nt].w ? sa[nt][3] : -INFINITY;
    }
    float t0 = fmaxf(fmaxf(sa[0][0], sa[0][1]), fmaxf(sa[0][2], sa[0][3]));
    float t1 = fmaxf(fmaxf(sa[1][0], sa[1][1]), fmaxf(sa[1][2], sa[1][3]));
    float t2 = fmaxf(fmaxf(sa[2][0], sa[2][1]), fmaxf(sa[2][2], sa[2][3]));
    float t3 = fmaxf(fmaxf(sa[3][0], sa[3][1]), fmaxf(sa[3][2], sa[3][3]));
    float tm = fmaxf(fmaxf(t0, t1), fmaxf(t2, t3));
    tm = fmaxf(tm, __shfl_xor(tm, 16));
    tm = fmaxf(tm, __shfl_xor(tm, 32));

    if (!__all(tm <= mrow + 8.0f)) {       // defer-max (T13)
      float nm = fmaxf(mrow, tm);
      float alpha = __expf(mrow - nm);
      mrow = nm;
      lrow *= alpha;
      float a0 = __shfl(alpha, lh * 4 + 0);
      float a1 = __shfl(alpha, lh * 4 + 1);
      float a2 = __shfl(alpha, lh * 4 + 2);
      float a3 = __shfl(alpha, lh * 4 + 3);
#pragma unroll
      for (int ht = 0; ht < 4; ht++) {
        o[ht][0] *= a0; o[ht][1] *= a1; o[ht][2] *= a2; o[ht][3] *= a3;
      }
    }

    float ts = 0.f;
#pragma unroll
    for (int nt = 0; nt < 4; nt++) {
#pragma unroll
      for (int r = 0; r < 4; r++) {
        float p = __expf(sa[nt][r] - mrow);
        sa[nt][r] = p;
        ts += p;
      }
    }
    ts += __shfl_xor(ts, 16);
    ts += __shfl_xor(ts, 32);
    lrow += ts;

#pragma unroll
    for (int nt = 0; nt < 4; nt++) {
      u32 plo = pk2(sa[nt][0], sa[nt][1]);
      u32 phi = pk2(sa[nt][2], sa[nt][3]);
      *(uint2*)&psw[(((nt * 32 + lh * 8) ^ swz) >> 1)] = make_uint2(plo, phi);
    }
    bf16x8 ap0 = *(const bf16x8*)(psw + koffA);
    bf16x8 ap1 = *(const bf16x8*)(psw + koffB);

    __builtin_amdgcn_s_setprio(1);
#pragma unroll
    for (int ht = 0; ht < 4; ht++) {
      o[ht] = __builtin_amdgcn_mfma_f32_16x16x32_bf16(ap0, vb[ht][0], o[ht], 0, 0, 0);
      o[ht] = __builtin_amdgcn_mfma_f32_16x16x32_bf16(ap1, vb[ht][1], o[ht], 0, 0, 0);
    }
    __builtin_amdgcn_s_setprio(0);
    __syncthreads();
    cur ^= 1;
  }
#undef STAGE_KV

#pragma unroll
  for (int r = 0; r < 4; r++) {
    int rr = q0 + w * 16 + lh * 4 + r;
    float* pob = po + ((size_t)z * NB * SEQ + (size_t)b * SEQ + rr) * 64;
#pragma unroll
    for (int ht = 0; ht < 4; ht++) pob[ht * 16 + l15] = o[ht][r];
  }
  if (lh == 0) {
    int rr = q0 + w * 16 + l15;
    pmp[(size_t)z * NB * SEQ + (size_t)b * SEQ + rr] = mrow;
    plp[(size_t)z * NB * SEQ + (size_t)b * SEQ + rr] = lrow;
  }
}

// ---------------- merge SPLIT partials -> fp32 out
__global__ __launch_bounds__(256) void merge_k(
    const float* __restrict__ po, const float* __restrict__ pmp,
    const float* __restrict__ plp, float* __restrict__ out) {
  int tid = threadIdx.x;
  int row = blockIdx.x * 32 + (tid >> 3);
  int c8 = (tid & 7) * 8;
  const int RT = NB * SEQ;

  float m[SPLIT], lv[SPLIT];
  float M = -INFINITY;
#pragma unroll
  for (int s = 0; s < SPLIT; s++) {
    m[s] = pmp[(size_t)s * RT + row];
    lv[s] = plp[(size_t)s * RT + row];
    M = fmaxf(M, m[s]);
  }
  float o8[8];
#pragma unroll
  for (int j = 0; j < 8; j++) o8[j] = 0.f;
  float L = 0.f;
  if (M != -INFINITY) {
#pragma unroll
    for (int s = 0; s < SPLIT; s++) {
      float ws = __expf(m[s] - M);
      L += ws * lv[s];
      const float* p = po + ((size_t)s * RT + row) * 64 + c8;
#pragma unroll
      for (int j = 0; j < 8; j++) o8[j] += ws * p[j];
    }
  }
  float inv = (L > 0.f) ? 1.0f / L : 0.f;
  float* op = out + (size_t)row * 64 + c8;
#pragma unroll
  for (int j = 0; j < 8; j++) op[j] = o8[j] * inv;
}

extern "C" void kernel_launch(void* const* d_in, const int* in_sizes, int n_in,
                              void* d_out, int out_size, void* d_ws, size_t ws_size,
                              hipStream_t stream) {
  const float* X   = (const float*)d_in[0];
  const int*   mrk = (const int*)d_in[1];
  const float* Wq  = (const float*)d_in[2];
  const float* Wk  = (const float*)d_in[3];
  const float* Wv  = (const float*)d_in[4];
  const float* Aq  = (const float*)d_in[5];
  const float* Bq  = (const float*)d_in[6];
  const float* Ak  = (const float*)d_in[7];
  const float* Bk  = (const float*)d_in[8];
  const float* Av  = (const float*)d_in[9];
  const float* Bv  = (const float*)d_in[10];

  u16* weff = (u16*)d_ws;
  u16* qws  = (u16*)((char*)d_ws + (512 << 10));
  u16* kws  = qws + (size_t)16384 * 64;
  u16* vws  = kws + (size_t)16384 * 64;
  float* po  = (float*)((char*)d_ws + ((size_t)6656 << 10));
  float* pmp = po + (size_t)SPLIT * 16384 * 64;
  float* plp = pmp + (size_t)SPLIT * 16384;

  (void)hipFuncSetAttribute((const void*)proj_k,
                            hipFuncAttributeMaxDynamicSharedMemorySize,
                            3 * XBUF + 2 * WBUF);

  fold_k<<<192, 256, 0, stream>>>(Wq, Wk, Wv, Aq, Bq, Ak, Bk, Av, Bv, weff);
  proj_k<<<512, 320, 3 * XBUF + 2 * WBUF, stream>>>(X, weff, qws, kws, vws);
  attn_k<<<dim3(32, 8, SPLIT), 256, 0, stream>>>(qws, kws, vws, mrk, po, pmp, plp);
  merge_k<<<512, 256, 0, stream>>>(po, pmp, plp, (float*)d_out);
}